// Round 2
// baseline (8665.506 us; speedup 1.0000x reference)
//
#include <hip/hip_runtime.h>
#include <hip/hip_bf16.h>
#include <math.h>

#define V 32000
#define D 256
#define L 4
#define E 4
#define S 4096
#define K_GATE 2201   // int(4096 * sigmoid(0.15)) = int(2201.31)

typedef __hip_bfloat16 bf16;

// Flag-branched float load: bf==1 -> bf16 array, bf==0 -> fp32 array.
// Branch is wave-uniform (flag identical for all lanes).
__device__ __forceinline__ float loadf(const void* p, size_t i, int bf) {
    if (bf) return __bfloat162float(((const bf16*)p)[i]);
    return ((const float*)p)[i];
}

// ---------------- runtime dtype detection ----------------
// emb ~ N(0, 0.02). If the buffer is bf16, even halfwords are bf16 samples
// (exponent field ~[113,124] -> "plausible"). If fp32, even halfwords are
// low mantissa halves (uniform bits, ~12% plausible). 64 samples, cut at 32.
__global__ void k_detect(const void* __restrict__ emb, int* __restrict__ flag) {
    const unsigned short* h = (const unsigned short*)emb;
    int cnt = 0;
    for (int i = 0; i < 128; i += 2) {
        int e = (h[i] >> 7) & 0xFF;
        if (e >= 100 && e <= 130) cnt++;
    }
    *flag = (cnt >= 32) ? 1 : 0;
}

// ---------------- embedding gather ----------------
__global__ void k_embed(const int* __restrict__ tok, const void* __restrict__ emb,
                        const int* __restrict__ bfp, float* __restrict__ x) {
    int s = blockIdx.x, d = threadIdx.x;
    int bf = *bfp;
    int t = tok[s];
    x[s * D + d] = loadf(emb, (size_t)t * D + d, bf);
}

// ---------------- AstroNorm stats: per-feature over sequence ----------------
__global__ void k_stats(const float* __restrict__ x, const void* __restrict__ buffers,
                        const void* __restrict__ decays, const int* __restrict__ bfp, int l,
                        float* __restrict__ mu, float* __restrict__ rstd,
                        float* __restrict__ absnb) {
    int d = blockIdx.x, t = threadIdx.x;
    int bf = *bfp;
    float sum = 0.f, sq = 0.f;
    for (int s = t; s < S; s += blockDim.x) {
        float v = x[s * D + d];
        sum += v; sq += v * v;
    }
    __shared__ float rs[256], rq[256];
    rs[t] = sum; rq[t] = sq;
    __syncthreads();
    for (int o = 128; o > 0; o >>= 1) {
        if (t < o) { rs[t] += rs[t + o]; rq[t] += rq[t + o]; }
        __syncthreads();
    }
    if (t == 0) {
        float m = rs[0] / (float)S;
        float var = (rq[0] - (float)S * m * m) / (float)(S - 1);  // ddof=1
        float dec = loadf(decays, l, bf);
        float nb = dec * loadf(buffers, l * D + d, bf) + (1.f - dec) * m;
        mu[d] = m;
        rstd[d] = rsqrtf(var + 1e-6f);
        absnb[d] = fabsf(nb);
    }
}

// ---------------- AstroNorm apply + context-gate score ----------------
__global__ void k_norm_score(float* __restrict__ x, const float* __restrict__ mu,
                             const float* __restrict__ rstd, const float* __restrict__ absnb,
                             const void* __restrict__ gate_w, const int* __restrict__ bfp,
                             int l, float* __restrict__ scores) {
    int s = blockIdx.x, d = threadIdx.x;
    int bf = *bfp;
    float m = mu[d];
    float v = x[s * D + d];
    float xv = (fabsf(v - m) > absnb[d]) ? m : v;
    xv *= rstd[d];
    x[s * D + d] = xv;
    __shared__ float red[256];
    red[d] = xv * loadf(gate_w, l * D + d, bf);
    __syncthreads();
    for (int o = 128; o > 0; o >>= 1) {
        if (d < o) red[d] += red[d + o];
        __syncthreads();
    }
    if (d == 0) scores[s] = red[0];
}

// ---------------- k-th largest score via single-block bitonic sort ----------------
__global__ void k_thr(const float* __restrict__ scores, float* __restrict__ thr) {
    __shared__ float a[S];
    int t = threadIdx.x;
    for (int i = t; i < S; i += blockDim.x) a[i] = scores[i];
    __syncthreads();
    for (int k = 2; k <= S; k <<= 1) {
        for (int j = k >> 1; j > 0; j >>= 1) {
            for (int i = t; i < S; i += blockDim.x) {
                int ixj = i ^ j;
                if (ixj > i) {
                    bool up = ((i & k) == 0);
                    float ai = a[i], aj = a[ixj];
                    if ((ai > aj) == up) { a[i] = aj; a[ixj] = ai; }
                }
            }
            __syncthreads();
        }
    }
    if (t == 0) thr[0] = a[S - K_GATE];  // ascending -> K_GATE-th largest
}

// ---------------- sparsity gate + expert router + 3-expert matvec ----------------
__global__ void k_expert(const float* __restrict__ x, const float* __restrict__ scores,
                         const float* __restrict__ thr,
                         const void* __restrict__ gating_W, const void* __restrict__ gating_b,
                         const void* __restrict__ exp_W, const void* __restrict__ exp_b,
                         const int* __restrict__ bfp, int l, float* __restrict__ xo) {
    int s = blockIdx.x, t = threadIdx.x;
    int bf = *bfp;
    __shared__ float xs[D];
    __shared__ float red[256];
    __shared__ float gsv[E];
    __shared__ int excl_s;
    float keep = (scores[s] > thr[0]) ? 1.f : 0.f;
    xs[t] = x[s * D + t] * keep;
    __syncthreads();
    for (int e = 0; e < E; e++) {
        red[t] = xs[t] * loadf(gating_W, (size_t)(l * E + e) * D + t, bf);
        __syncthreads();
        for (int o = 128; o > 0; o >>= 1) {
            if (t < o) red[t] += red[t + o];
            __syncthreads();
        }
        if (t == 0) gsv[e] = red[0] + loadf(gating_b, l * E + e, bf);
        __syncthreads();
    }
    if (t == 0) {
        // excluded expert = argmin; ties -> largest index (top_k keeps lower indices)
        int mi = 0; float mv = gsv[0];
        for (int e = 1; e < E; e++) {
            if (gsv[e] <= mv) { mv = gsv[e]; mi = e; }
        }
        excl_s = mi;
    }
    __syncthreads();
    int excl = excl_s;
    float acc = 0.f;
    for (int e = 0; e < E; e++) {
        if (e == excl) continue;
        size_t wb = ((size_t)(l * E + e) * D + t) * D;
        float a = 0.f;
        #pragma unroll 8
        for (int d = 0; d < D; d++) a += loadf(exp_W, wb + d, bf) * xs[d];
        acc += a + loadf(exp_b, (size_t)(l * E + e) * D + t, bf);
    }
    xo[s * D + t] = acc;
}

// ---------------- final LayerNorm ----------------
__global__ void k_ln(const float* __restrict__ x, const void* __restrict__ g,
                     const void* __restrict__ b, const int* __restrict__ bfp,
                     float* __restrict__ xn) {
    int s = blockIdx.x, t = threadIdx.x;
    int bf = *bfp;
    __shared__ float rs[256], rq[256];
    float v = x[s * D + t];
    rs[t] = v; rq[t] = v * v;
    __syncthreads();
    for (int o = 128; o > 0; o >>= 1) {
        if (t < o) { rs[t] += rs[t + o]; rq[t] += rq[t + o]; }
        __syncthreads();
    }
    float m = rs[0] / (float)D;
    float var = rq[0] / (float)D - m * m;   // biased
    float r = rsqrtf(var + 1e-5f);
    xn[s * D + t] = (v - m) * r * loadf(g, t, bf) + loadf(b, t, bf);
}

// ---------------- vocab head: C[s,v] = xn[s,:] . W[v,:] + bias[v] ----------------
#define BM 64
#define BN 64
#define BK 32
__global__ __launch_bounds__(256) void k_head(const float* __restrict__ xn,
                                              const void* __restrict__ W,
                                              const void* __restrict__ bias,
                                              const int* __restrict__ bfp,
                                              void* __restrict__ out) {
    __shared__ float As[BK][BM + 1];
    __shared__ float Bs[BK][BN + 1];
    int bf = *bfp;
    int bs = blockIdx.y * BM;   // token tile
    int bv = blockIdx.x * BN;   // vocab tile
    int t = threadIdx.x;
    int tm = (t >> 4) << 2;
    int tn = (t & 15) << 2;
    float acc[4][4] = {};
    for (int k0 = 0; k0 < D; k0 += BK) {
        for (int i = t; i < BM * BK; i += 256) {
            int m = i >> 5, k = i & 31;
            As[k][m] = xn[(size_t)(bs + m) * D + k0 + k];
        }
        for (int i = t; i < BN * BK; i += 256) {
            int n = i >> 5, k = i & 31;
            Bs[k][n] = loadf(W, (size_t)(bv + n) * D + k0 + k, bf);
        }
        __syncthreads();
        for (int k = 0; k < BK; k++) {
            float a[4], bb[4];
            #pragma unroll
            for (int i = 0; i < 4; i++) a[i] = As[k][tm + i];
            #pragma unroll
            for (int j = 0; j < 4; j++) bb[j] = Bs[k][tn + j];
            #pragma unroll
            for (int i = 0; i < 4; i++)
                #pragma unroll
                for (int j = 0; j < 4; j++)
                    acc[i][j] += a[i] * bb[j];
        }
        __syncthreads();
    }
    #pragma unroll
    for (int i = 0; i < 4; i++) {
        #pragma unroll
        for (int j = 0; j < 4; j++) {
            int sm = bs + tm + i, vn = bv + tn + j;
            float v = acc[i][j] + loadf(bias, vn, bf);
            size_t o = (size_t)sm * V + vn;
            if (bf) ((bf16*)out)[o] = __float2bfloat16(v);
            else    ((float*)out)[o] = v;
        }
    }
}

extern "C" void kernel_launch(void* const* d_in, const int* in_sizes, int n_in,
                              void* d_out, int out_size, void* d_ws, size_t ws_size,
                              hipStream_t stream) {
    const int*  tokens   = (const int*)d_in[0];
    const void* emb      = d_in[1];
    const void* buffers  = d_in[2];
    const void* decays   = d_in[3];
    const void* gate_w   = d_in[4];
    const void* gating_W = d_in[5];
    const void* gating_b = d_in[6];
    const void* exp_W    = d_in[7];
    const void* exp_b    = d_in[8];
    const void* ln_g     = d_in[9];
    const void* ln_b     = d_in[10];
    const void* head_W   = d_in[11];
    const void* head_b   = d_in[12];

    float* ws     = (float*)d_ws;
    float* xA     = ws;                 // S*D
    float* xB     = xA + S * D;         // S*D
    float* xn     = xB + S * D;         // S*D
    float* scores = xn + S * D;         // S
    float* mu     = scores + S;         // D
    float* rstd   = mu + D;             // D
    float* absnb  = rstd + D;           // D
    float* thr    = absnb + D;          // 1
    int*   flag   = (int*)(thr + 1);    // 1

    k_detect<<<1, 1, 0, stream>>>(emb, flag);
    k_embed<<<S, D, 0, stream>>>(tokens, emb, flag, xA);
    float* xc = xA;
    float* xo = xB;
    for (int l = 0; l < L; l++) {
        k_stats<<<D, 256, 0, stream>>>(xc, buffers, decays, flag, l, mu, rstd, absnb);
        k_norm_score<<<S, 256, 0, stream>>>(xc, mu, rstd, absnb, gate_w, flag, l, scores);
        k_thr<<<1, 1024, 0, stream>>>(scores, thr);
        k_expert<<<S, 256, 0, stream>>>(xc, scores, thr, gating_W, gating_b,
                                        exp_W, exp_b, flag, l, xo);
        float* tmp = xc; xc = xo; xo = tmp;
    }
    k_ln<<<S, 256, 0, stream>>>(xc, ln_g, ln_b, flag, xn);
    dim3 g(V / BN, S / BM);
    k_head<<<g, 256, 0, stream>>>(xn, head_W, head_b, flag, d_out);
}

// Round 3
// 1332.203 us; speedup vs baseline: 6.5046x; 6.5046x over previous
//
#include <hip/hip_runtime.h>
#include <hip/hip_bf16.h>
#include <math.h>

#define V 32000
#define D 256
#define L 4
#define E 4
#define S 4096
#define K_GATE 2201   // int(4096 * sigmoid(0.15)) = int(2201.31)
#define NE 1024       // E*D: concatenated expert output width
#define NCH 64        // stats chunks
#define SCHUNK 64     // tokens per stats chunk

typedef __hip_bfloat16 bf16;
typedef __attribute__((ext_vector_type(8))) short bf16x8;
typedef __attribute__((ext_vector_type(4))) float f32x4;

__device__ __forceinline__ float loadf(const void* p, size_t i, int bf) {
    if (bf) return __bfloat162float(((const bf16*)p)[i]);
    return ((const float*)p)[i];
}

// ---------------- runtime dtype detection (bf16 vs fp32 inputs) ----------------
__global__ void k_detect(const void* __restrict__ emb, int* __restrict__ flag) {
    const unsigned short* h = (const unsigned short*)emb;
    int cnt = 0;
    for (int i = 0; i < 128; i += 2) {
        int e = (h[i] >> 7) & 0xFF;
        if (e >= 100 && e <= 130) cnt++;
    }
    *flag = (cnt >= 32) ? 1 : 0;
}

// ---------------- head weight -> bf16 (copy or convert) ----------------
__global__ void k_wcast(const void* __restrict__ W, const int* __restrict__ bfp,
                        bf16* __restrict__ Wb) {
    int bf = *bfp;
    size_t idx = ((size_t)blockIdx.x * 256 + threadIdx.x) * 4;
    if (bf) {
        ushort4 v = *(const ushort4*)((const unsigned short*)W + idx);
        *(ushort4*)((unsigned short*)Wb + idx) = v;
    } else {
        float4 v = *(const float4*)((const float*)W + idx);
        Wb[idx + 0] = __float2bfloat16(v.x);
        Wb[idx + 1] = __float2bfloat16(v.y);
        Wb[idx + 2] = __float2bfloat16(v.z);
        Wb[idx + 3] = __float2bfloat16(v.w);
    }
}

// ---------------- embedding gather ----------------
__global__ void k_embed(const int* __restrict__ tok, const void* __restrict__ emb,
                        const int* __restrict__ bfp, float* __restrict__ x) {
    int s = blockIdx.x, d = threadIdx.x;
    int bf = *bfp;
    int t = tok[s];
    x[s * D + d] = loadf(emb, (size_t)t * D + d, bf);
}

// ---------------- AstroNorm stats, phase 1: coalesced partial sums ----------------
__global__ void k_stats_part(const float* __restrict__ x, float* __restrict__ psum,
                             float* __restrict__ psq) {
    int b = blockIdx.x;        // NCH blocks
    int t = threadIdx.x;       // 256 = one feature per thread
    float s = 0.f, q = 0.f;
    int s0 = b * SCHUNK;
    #pragma unroll 4
    for (int i = 0; i < SCHUNK; i++) {
        float v = x[(size_t)(s0 + i) * D + t];
        s += v; q += v * v;
    }
    psum[b * D + t] = s;
    psq[b * D + t] = q;
}

// ---------------- AstroNorm stats, phase 2: finalize ----------------
__global__ void k_stats_fin(const float* __restrict__ psum, const float* __restrict__ psq,
                            const void* __restrict__ buffers, const void* __restrict__ decays,
                            const int* __restrict__ bfp, int l,
                            float* __restrict__ mu, float* __restrict__ rstd,
                            float* __restrict__ absnb) {
    int t = threadIdx.x;       // 256
    int bf = *bfp;
    float s = 0.f, q = 0.f;
    for (int b = 0; b < NCH; b++) { s += psum[b * D + t]; q += psq[b * D + t]; }
    float m = s / (float)S;
    float var = (q - (float)S * m * m) / (float)(S - 1);   // ddof=1
    float dec = loadf(decays, l, bf);
    float nb = dec * loadf(buffers, l * D + t, bf) + (1.f - dec) * m;
    mu[t] = m;
    rstd[t] = rsqrtf(var + 1e-6f);
    absnb[t] = fabsf(nb);
}

// ---------------- AstroNorm apply + context-gate score ----------------
__global__ void k_norm_score(float* __restrict__ x, const float* __restrict__ mu,
                             const float* __restrict__ rstd, const float* __restrict__ absnb,
                             const void* __restrict__ gate_w, const int* __restrict__ bfp,
                             int l, float* __restrict__ scores) {
    int s = blockIdx.x, d = threadIdx.x;
    int bf = *bfp;
    float m = mu[d];
    float v = x[s * D + d];
    float xv = (fabsf(v - m) > absnb[d]) ? m : v;
    xv *= rstd[d];
    x[s * D + d] = xv;
    __shared__ float red[256];
    red[d] = xv * loadf(gate_w, l * D + d, bf);
    __syncthreads();
    for (int o = 128; o > 0; o >>= 1) {
        if (d < o) red[d] += red[d + o];
        __syncthreads();
    }
    if (d == 0) scores[s] = red[0];
}

// ---------------- k-th largest via exact MSB radix select ----------------
__global__ void k_thr(const float* __restrict__ scores, float* __restrict__ thr) {
    __shared__ unsigned int keys[S];
    __shared__ unsigned int hist[256];
    __shared__ unsigned int sh_prefix, sh_rank;
    int t = threadIdx.x;                     // 1024 threads
    for (int i = t; i < S; i += 1024) {
        unsigned int u = __float_as_uint(scores[i]);
        keys[i] = (u & 0x80000000u) ? ~u : (u | 0x80000000u);   // ascending-monotone
    }
    if (t == 0) { sh_prefix = 0u; sh_rank = S - K_GATE; }        // 0-based ascending rank
    __syncthreads();
    for (int shift = 24; shift >= 0; shift -= 8) {
        if (t < 256) hist[t] = 0u;
        __syncthreads();
        unsigned int pmask = (shift == 24) ? 0u : (0xFFFFFFFFu << (shift + 8));
        unsigned int pref = sh_prefix;
        for (int i = t; i < S; i += 1024) {
            unsigned int k = keys[i];
            if ((k & pmask) == pref)
                atomicAdd(&hist[(k >> shift) & 0xFF], 1u);
        }
        __syncthreads();
        if (t == 0) {
            unsigned int r = sh_rank, cum = 0u;
            int b = 0;
            for (; b < 256; b++) {
                if (cum + hist[b] > r) break;
                cum += hist[b];
            }
            sh_rank = r - cum;
            sh_prefix = pref | ((unsigned int)b << shift);
        }
        __syncthreads();
    }
    if (t == 0) {
        unsigned int k = sh_prefix;
        unsigned int u = (k & 0x80000000u) ? (k ^ 0x80000000u) : ~k;
        thr[0] = __uint_as_float(u);
    }
}

// ---------------- gate mask + expert router ----------------
__global__ void k_route(const float* __restrict__ x, const float* __restrict__ scores,
                        const float* __restrict__ thr,
                        const void* __restrict__ gating_W, const void* __restrict__ gating_b,
                        const int* __restrict__ bfp, int l,
                        float* __restrict__ xg, int* __restrict__ excl) {
    int s = blockIdx.x, t = threadIdx.x;
    int bf = *bfp;
    __shared__ float red[256];
    __shared__ float gsv[E];
    float keep = (scores[s] > thr[0]) ? 1.f : 0.f;
    float xv = x[s * D + t] * keep;
    xg[s * D + t] = xv;
    for (int e = 0; e < E; e++) {
        red[t] = xv * loadf(gating_W, (size_t)(l * E + e) * D + t, bf);
        __syncthreads();
        for (int o = 128; o > 0; o >>= 1) {
            if (t < o) red[t] += red[t + o];
            __syncthreads();
        }
        if (t == 0) gsv[e] = red[0] + loadf(gating_b, l * E + e, bf);
        __syncthreads();
    }
    if (t == 0) {
        // excluded expert = argmin; ties -> largest index (top_k keeps lower indices)
        int mi = 0; float mv = gsv[0];
        for (int e = 1; e < E; e++) if (gsv[e] <= mv) { mv = gsv[e]; mi = e; }
        excl[s] = mi;
    }
}

// ---------------- all-expert GEMM: Y[s][e*256+o] = xg[s,:].exp_W[l,e,o,:] ----------------
#define BM 64
#define BN 64
#define BK 32
__global__ __launch_bounds__(256) void k_egemm(const float* __restrict__ xg,
                                               const void* __restrict__ exp_W,
                                               const int* __restrict__ bfp, int l,
                                               float* __restrict__ Y) {
    __shared__ float As[BK][BM + 1];
    __shared__ float Bs[BK][BN + 1];
    int bf = *bfp;
    int bn = blockIdx.x * BN;   // expert-output col in [0,NE)
    int bm = blockIdx.y * BM;   // token tile
    int t = threadIdx.x;
    int tm = (t >> 4) << 2;
    int tn = (t & 15) << 2;
    float acc[4][4] = {};
    for (int k0 = 0; k0 < D; k0 += BK) {
        for (int i = t; i < BM * BK; i += 256) {
            int m = i >> 5, k = i & 31;
            As[k][m] = xg[(size_t)(bm + m) * D + k0 + k];
        }
        for (int i = t; i < BN * BK; i += 256) {
            int n = i >> 5, k = i & 31;
            int gn = bn + n;
            int e = gn >> 8, o = gn & 255;
            Bs[k][n] = loadf(exp_W, ((size_t)((l * E + e) * D + o)) * D + k0 + k, bf);
        }
        __syncthreads();
        for (int k = 0; k < BK; k++) {
            float a[4], bb[4];
            #pragma unroll
            for (int i = 0; i < 4; i++) a[i] = As[k][tm + i];
            #pragma unroll
            for (int j = 0; j < 4; j++) bb[j] = Bs[k][tn + j];
            #pragma unroll
            for (int i = 0; i < 4; i++)
                #pragma unroll
                for (int j = 0; j < 4; j++)
                    acc[i][j] += a[i] * bb[j];
        }
        __syncthreads();
    }
    #pragma unroll
    for (int i = 0; i < 4; i++)
        #pragma unroll
        for (int j = 0; j < 4; j++)
            Y[(size_t)(bm + tm + i) * NE + bn + tn + j] = acc[i][j];
}

// ---------------- combine 3 selected experts + bias ----------------
__global__ void k_combine(const float* __restrict__ Y, const int* __restrict__ excl,
                          const void* __restrict__ exp_b, const int* __restrict__ bfp,
                          int l, float* __restrict__ xo) {
    int s = blockIdx.x, t = threadIdx.x;
    int bf = *bfp;
    int ex = excl[s];
    float a = 0.f;
    for (int e = 0; e < E; e++) {
        if (e == ex) continue;
        a += Y[(size_t)s * NE + e * D + t] + loadf(exp_b, (size_t)(l * E + e) * D + t, bf);
    }
    xo[s * D + t] = a;
}

// ---------------- final LayerNorm -> bf16 ----------------
__global__ void k_ln(const float* __restrict__ x, const void* __restrict__ g,
                     const void* __restrict__ b, const int* __restrict__ bfp,
                     bf16* __restrict__ xnb) {
    int s = blockIdx.x, t = threadIdx.x;
    int bf = *bfp;
    __shared__ float rs[256], rq[256];
    float v = x[s * D + t];
    rs[t] = v; rq[t] = v * v;
    __syncthreads();
    for (int o = 128; o > 0; o >>= 1) {
        if (t < o) { rs[t] += rs[t + o]; rq[t] += rq[t + o]; }
        __syncthreads();
    }
    float m = rs[0] / (float)D;
    float var = rq[0] / (float)D - m * m;   // biased
    float r = rsqrtf(var + 1e-5f);
    xnb[s * D + t] = __float2bfloat16((v - m) * r * loadf(g, t, bf) + loadf(b, t, bf));
}

// ---------------- vocab head: MFMA bf16, 128x128 tile, K=256 ----------------
// A/B frag: idx=lane&15 (m/n), k=quad*8+j. C/D: col=lane&15, row=quad*4+reg.
__global__ __launch_bounds__(256) void k_head_mfma(const bf16* __restrict__ xnb,
                                                   const bf16* __restrict__ Wb,
                                                   const void* __restrict__ bias,
                                                   const int* __restrict__ bfp,
                                                   void* __restrict__ out) {
    __shared__ short At[128][40];   // +8 pad: 2-way LDS conflict (free)
    __shared__ short Bt[128][40];
    int bf = *bfp;
    int bs = blockIdx.x * 128;      // token tile (x fastest -> W-tile L2 reuse)
    int bv = blockIdx.y * 128;      // vocab tile
    int t = threadIdx.x;
    int wave = t >> 6, lane = t & 63;
    int wm = (wave >> 1) * 64;      // wave sub-tile origin
    int wn = (wave & 1) * 64;
    int quad = lane >> 4, l16 = lane & 15;
    int r = t >> 1;                 // staging row 0..127
    int c = (t & 1) * 16;           // staging col 0 or 16

    f32x4 acc[4][4] = {};
    for (int k0 = 0; k0 < D; k0 += 32) {
        *(bf16x8*)&At[r][c]     = *(const bf16x8*)(xnb + (size_t)(bs + r) * D + k0 + c);
        *(bf16x8*)&At[r][c + 8] = *(const bf16x8*)(xnb + (size_t)(bs + r) * D + k0 + c + 8);
        *(bf16x8*)&Bt[r][c]     = *(const bf16x8*)(Wb + (size_t)(bv + r) * D + k0 + c);
        *(bf16x8*)&Bt[r][c + 8] = *(const bf16x8*)(Wb + (size_t)(bv + r) * D + k0 + c + 8);
        __syncthreads();
        bf16x8 af[4], bfg[4];
        #pragma unroll
        for (int i = 0; i < 4; i++) af[i]  = *(const bf16x8*)&At[wm + i * 16 + l16][quad * 8];
        #pragma unroll
        for (int j = 0; j < 4; j++) bfg[j] = *(const bf16x8*)&Bt[wn + j * 16 + l16][quad * 8];
        #pragma unroll
        for (int i = 0; i < 4; i++)
            #pragma unroll
            for (int j = 0; j < 4; j++)
                acc[i][j] = __builtin_amdgcn_mfma_f32_16x16x32_bf16(af[i], bfg[j], acc[i][j], 0, 0, 0);
        __syncthreads();
    }
    #pragma unroll
    for (int j = 0; j < 4; j++) {
        int col = bv + wn + j * 16 + l16;
        float bv_ = loadf(bias, col, bf);
        #pragma unroll
        for (int i = 0; i < 4; i++) {
            int row0 = bs + wm + i * 16 + quad * 4;
            #pragma unroll
            for (int rg = 0; rg < 4; rg++) {
                float v = acc[i][j][rg] + bv_;
                size_t o = (size_t)(row0 + rg) * V + col;
                if (bf) ((bf16*)out)[o] = __float2bfloat16(v);
                else    ((float*)out)[o] = v;
            }
        }
    }
}

extern "C" void kernel_launch(void* const* d_in, const int* in_sizes, int n_in,
                              void* d_out, int out_size, void* d_ws, size_t ws_size,
                              hipStream_t stream) {
    const int*  tokens   = (const int*)d_in[0];
    const void* emb      = d_in[1];
    const void* buffers  = d_in[2];
    const void* decays   = d_in[3];
    const void* gate_w   = d_in[4];
    const void* gating_W = d_in[5];
    const void* gating_b = d_in[6];
    const void* exp_W    = d_in[7];
    const void* exp_b    = d_in[8];
    const void* ln_g     = d_in[9];
    const void* ln_b     = d_in[10];
    const void* head_W   = d_in[11];
    const void* head_b   = d_in[12];

    // ws layout (bf16 arrays first for 16B alignment)
    char* p = (char*)d_ws;
    bf16* Wb   = (bf16*)p;              p += (size_t)V * D * 2;      // 16.38 MB
    bf16* xnb  = (bf16*)p;              p += (size_t)S * D * 2;      // 2.1 MB
    float* xA  = (float*)p;             p += (size_t)S * D * 4;      // 4 MB
    float* xB  = (float*)p;             p += (size_t)S * D * 4;
    float* xg  = (float*)p;             p += (size_t)S * D * 4;
    float* Y   = (float*)p;             p += (size_t)S * NE * 4;     // 16 MB
    float* psum = (float*)p;            p += (size_t)NCH * D * 4;
    float* psq  = (float*)p;            p += (size_t)NCH * D * 4;
    float* scores = (float*)p;          p += (size_t)S * 4;
    float* mu   = (float*)p;            p += D * 4;
    float* rstd = (float*)p;            p += D * 4;
    float* absnb = (float*)p;           p += D * 4;
    float* thr  = (float*)p;            p += 16;
    int* flag   = (int*)p;              p += 16;
    int* excl   = (int*)p;              p += (size_t)S * 4;

    k_detect<<<1, 1, 0, stream>>>(emb, flag);
    k_wcast<<<(V * D) / 1024, 256, 0, stream>>>(head_W, flag, Wb);
    k_embed<<<S, D, 0, stream>>>(tokens, emb, flag, xA);

    float* xc = xA;
    float* xo = xB;
    for (int l = 0; l < L; l++) {
        k_stats_part<<<NCH, 256, 0, stream>>>(xc, psum, psq);
        k_stats_fin<<<1, 256, 0, stream>>>(psum, psq, buffers, decays, flag, l, mu, rstd, absnb);
        k_norm_score<<<S, 256, 0, stream>>>(xc, mu, rstd, absnb, gate_w, flag, l, scores);
        k_thr<<<1, 1024, 0, stream>>>(scores, thr);
        k_route<<<S, 256, 0, stream>>>(xc, scores, thr, gating_W, gating_b, flag, l, xg, excl);
        dim3 ge(NE / BN, S / BM);
        k_egemm<<<ge, 256, 0, stream>>>(xg, exp_W, flag, l, Y);
        k_combine<<<S, 256, 0, stream>>>(Y, excl, exp_b, flag, l, xo);
        float* tmp = xc; xc = xo; xo = tmp;
    }
    k_ln<<<S, 256, 0, stream>>>(xc, ln_g, ln_b, flag, xnb);
    dim3 gh(S / 128, V / 128);
    k_head_mfma<<<gh, 256, 0, stream>>>(xnb, Wb, head_b, flag, d_out);
}

// Round 8
// 1180.218 us; speedup vs baseline: 7.3423x; 1.1288x over previous
//
#include <hip/hip_runtime.h>
#include <hip/hip_bf16.h>
#include <math.h>

#define V 32000
#define D 256
#define L 4
#define E 4
#define S 4096
#define K_GATE 2201   // int(4096 * sigmoid(0.15)) = int(2201.31)
#define NE 1024       // E*D: concatenated expert output width
#define NCH 64        // stats chunks
#define SCHUNK 64     // tokens per stats chunk
#define CTS 136       // head C-tile LDS row stride (shorts); 272B=17*16 -> rows 16B-aligned

// R8: bisect conclusion (R4-R7): the split-precision MFMA egemm was the sole
// error source (absmax tracked split width; R5==R6==R7 bit-identical). Expert
// GEMM must stay fp32-exact -> R3's VALU egemm restored verbatim. All other
// R5 components are measurement-exonerated (bit-identical output) and kept.

typedef __hip_bfloat16 bf16;
typedef __attribute__((ext_vector_type(8))) short bf16x8;
typedef __attribute__((ext_vector_type(4))) float f32x4;

__device__ __forceinline__ float loadf(const void* p, size_t i, int bf) {
    if (bf) return __bfloat162float(((const bf16*)p)[i]);
    return ((const float*)p)[i];
}

// async global->LDS, 16B per lane; LDS dest = wave-uniform base + lane*16
#define GLDS16(g, l)                                                            \
    __builtin_amdgcn_global_load_lds(                                           \
        (const __attribute__((address_space(1))) unsigned int*)(g),             \
        (__attribute__((address_space(3))) unsigned int*)(l), 16, 0, 0)

// Stage a 128x32 bf16 tile (8 KB) with XOR chunk swizzle (exonerated: R5/R6
// bit-identical outputs). frag ds_read_b128 lands ~2-way conflict (free).
__device__ __forceinline__ void stage_tile(const bf16* __restrict__ src, int rowStride,
                                           short* lds, int t, int k0) {
    int w = t >> 6, l = t & 63;
    #pragma unroll
    for (int i = 0; i < 2; i++) {
        int chunk = (w * 2 + i) * 64 + l;
        int row = chunk >> 2;
        int c8 = (chunk & 3) ^ ((row >> 1) & 3);
        const bf16* g = src + (size_t)row * rowStride + k0 + c8 * 8;
        GLDS16(g, (char*)lds + (size_t)(w * 2 + i) * 1024);
    }
}

__device__ __forceinline__ bf16x8 frag_ld(const short* lds, int row, int quad) {
    return *(const bf16x8*)&lds[row * 32 + ((quad ^ ((row >> 1) & 3)) << 3)];
}

// ---------------- runtime dtype detection (bf16 vs fp32 inputs) ----------------
__global__ void k_detect(const void* __restrict__ emb, int* __restrict__ flag) {
    const unsigned short* h = (const unsigned short*)emb;
    int cnt = 0;
    for (int i = 0; i < 128; i += 2) {
        int e = (h[i] >> 7) & 0xFF;
        if (e >= 100 && e <= 130) cnt++;
    }
    *flag = (cnt >= 32) ? 1 : 0;
}

// ---------------- head weight -> bf16 (fp32-input fallback only) ----------------
__global__ void k_wcast(const void* __restrict__ W, const int* __restrict__ bfp,
                        bf16* __restrict__ Wb) {
    if (*bfp) return;   // bf16 inputs: head reads W directly
    size_t idx = ((size_t)blockIdx.x * 256 + threadIdx.x) * 4;
    float4 v = *(const float4*)((const float*)W + idx);
    Wb[idx + 0] = __float2bfloat16(v.x);
    Wb[idx + 1] = __float2bfloat16(v.y);
    Wb[idx + 2] = __float2bfloat16(v.z);
    Wb[idx + 3] = __float2bfloat16(v.w);
}

// ---------------- embedding gather ----------------
__global__ void k_embed(const int* __restrict__ tok, const void* __restrict__ emb,
                        const int* __restrict__ bfp, float* __restrict__ x) {
    int s = blockIdx.x, d = threadIdx.x;
    int bf = *bfp;
    int t = tok[s];
    x[s * D + d] = loadf(emb, (size_t)t * D + d, bf);
}

// ---------------- AstroNorm stats, phase 1: coalesced partial sums ----------------
__global__ void k_stats_part(const float* __restrict__ x, float* __restrict__ psum,
                             float* __restrict__ psq) {
    int b = blockIdx.x;        // NCH blocks
    int t = threadIdx.x;       // 256 = one feature per thread
    float s = 0.f, q = 0.f;
    int s0 = b * SCHUNK;
    #pragma unroll 4
    for (int i = 0; i < SCHUNK; i++) {
        float v = x[(size_t)(s0 + i) * D + t];
        s += v; q += v * v;
    }
    psum[b * D + t] = s;
    psq[b * D + t] = q;
}

// ---------------- AstroNorm stats, phase 2: finalize ----------------
__global__ void k_stats_fin(const float* __restrict__ psum, const float* __restrict__ psq,
                            const void* __restrict__ buffers, const void* __restrict__ decays,
                            const int* __restrict__ bfp, int l,
                            float* __restrict__ mu, float* __restrict__ rstd,
                            float* __restrict__ absnb) {
    int t = threadIdx.x;       // 256
    int bf = *bfp;
    float s = 0.f, q = 0.f;
    for (int b = 0; b < NCH; b++) { s += psum[b * D + t]; q += psq[b * D + t]; }
    float m = s / (float)S;
    float var = (q - (float)S * m * m) / (float)(S - 1);   // ddof=1
    float dec = loadf(decays, l, bf);
    float nb = dec * loadf(buffers, l * D + t, bf) + (1.f - dec) * m;
    mu[t] = m;
    rstd[t] = rsqrtf(var + 1e-6f);
    absnb[t] = fabsf(nb);
}

// ---------------- AstroNorm apply + context-gate score (wave per token) ----------
__global__ void k_norm_score(float* __restrict__ x, const float* __restrict__ mu,
                             const float* __restrict__ rstd, const float* __restrict__ absnb,
                             const void* __restrict__ gate_w, const int* __restrict__ bfp,
                             int l, float* __restrict__ scores) {
    int t = threadIdx.x, w = t >> 6, ln = t & 63;
    int s = blockIdx.x * 4 + w;
    int bf = *bfp;
    float part = 0.f;
    #pragma unroll
    for (int j = 0; j < 4; j++) {
        int f = ln + j * 64;
        float m = mu[f];
        float v = x[(size_t)s * D + f];
        float xv = (fabsf(v - m) > absnb[f]) ? m : v;
        xv *= rstd[f];
        x[(size_t)s * D + f] = xv;
        part += xv * loadf(gate_w, l * D + f, bf);
    }
    #pragma unroll
    for (int m2 = 1; m2 < 64; m2 <<= 1) part += __shfl_xor(part, m2, 64);
    if (ln == 0) scores[s] = part;
}

// ---------------- k-th largest via exact MSB radix select (parallel scan) --------
__global__ void k_thr(const float* __restrict__ scores, float* __restrict__ thr) {
    __shared__ unsigned keys[S];
    __shared__ unsigned hist[256];
    __shared__ unsigned scanb[256];
    __shared__ unsigned sh_pref, sh_rank, sh_bucket;
    int t = threadIdx.x;                     // 256 threads
    for (int i = t; i < S; i += 256) {
        unsigned u = __float_as_uint(scores[i]);
        keys[i] = (u & 0x80000000u) ? ~u : (u | 0x80000000u);   // ascending-monotone
    }
    if (t == 0) { sh_pref = 0u; sh_rank = S - K_GATE; }          // 0-based ascending rank
    __syncthreads();
    for (int shift = 24; shift >= 0; shift -= 8) {
        unsigned pref = sh_pref, r = sh_rank;
        unsigned pmask = (shift == 24) ? 0u : (0xFFFFFFFFu << (shift + 8));
        hist[t] = 0u;
        __syncthreads();
        for (int i = t; i < S; i += 256) {
            unsigned k = keys[i];
            if ((k & pmask) == pref) atomicAdd(&hist[(k >> shift) & 0xFF], 1u);
        }
        __syncthreads();
        unsigned v = hist[t];
        scanb[t] = v;
        __syncthreads();
        for (int o = 1; o < 256; o <<= 1) {
            unsigned u2 = (t >= o) ? scanb[t - o] : 0u;
            __syncthreads();
            scanb[t] += u2;
            __syncthreads();
        }
        unsigned incl = scanb[t], exc = incl - v;
        if (exc <= r && r < incl) {          // exactly one thread matches (v>0)
            sh_bucket = t;
            sh_rank = r - exc;
        }
        __syncthreads();
        if (t == 0) sh_pref = pref | (sh_bucket << shift);
        __syncthreads();
    }
    if (t == 0) {
        unsigned k = sh_pref;
        unsigned u = (k & 0x80000000u) ? (k ^ 0x80000000u) : ~k;
        thr[0] = __uint_as_float(u);
    }
}

// ---------------- gate mask + expert router (wave per token), fp32 xg ------------
__global__ void k_route(const float* __restrict__ x, const float* __restrict__ scores,
                        const float* __restrict__ thr,
                        const void* __restrict__ gating_W, const void* __restrict__ gating_b,
                        const int* __restrict__ bfp, int l,
                        float* __restrict__ xg, int* __restrict__ excl) {
    int t = threadIdx.x, w = t >> 6, ln = t & 63;
    int s = blockIdx.x * 4 + w;
    int bf = *bfp;
    float keep = (scores[s] > thr[0]) ? 1.f : 0.f;
    float xv[4];
    #pragma unroll
    for (int j = 0; j < 4; j++) {
        int f = ln + j * 64;
        float v = x[(size_t)s * D + f] * keep;
        xv[j] = v;
        xg[(size_t)s * D + f] = v;
    }
    float gs[E];
    #pragma unroll
    for (int e = 0; e < E; e++) {
        float p = 0.f;
        #pragma unroll
        for (int j = 0; j < 4; j++)
            p += xv[j] * loadf(gating_W, (size_t)(l * E + e) * D + ln + j * 64, bf);
        #pragma unroll
        for (int m2 = 1; m2 < 64; m2 <<= 1) p += __shfl_xor(p, m2, 64);
        gs[e] = p + loadf(gating_b, l * E + e, bf);
    }
    if (ln == 0) {
        // excluded = argmin; ties -> largest index (top_k keeps lower indices)
        int mi = 0; float mv = gs[0];
        #pragma unroll
        for (int e = 1; e < E; e++) if (gs[e] <= mv) { mv = gs[e]; mi = e; }
        excl[s] = mi;
    }
}

// ---------------- all-expert GEMM, fp32 VALU (R3-proven verbatim) ----------------
// NOTE: must stay fp32-exact — bf16 split-MFMA here flipped trunk threshold
// comparisons (R4-R7 failures). Y[s][gn] = xg[s,:].exp_W[l,gn,:]
#define BM 64
#define BN 64
#define BK 32
__global__ __launch_bounds__(256) void k_egemm(const float* __restrict__ xg,
                                               const void* __restrict__ exp_W,
                                               const int* __restrict__ bfp, int l,
                                               float* __restrict__ Y) {
    __shared__ float As[BK][BM + 1];
    __shared__ float Bs[BK][BN + 1];
    int bf = *bfp;
    int bn = blockIdx.x * BN;   // expert-output col in [0,NE)
    int bm = blockIdx.y * BM;   // token tile
    int t = threadIdx.x;
    int tm = (t >> 4) << 2;
    int tn = (t & 15) << 2;
    float acc[4][4] = {};
    for (int k0 = 0; k0 < D; k0 += BK) {
        for (int i = t; i < BM * BK; i += 256) {
            int m = i >> 5, k = i & 31;
            As[k][m] = xg[(size_t)(bm + m) * D + k0 + k];
        }
        for (int i = t; i < BN * BK; i += 256) {
            int n = i >> 5, k = i & 31;
            int gn = bn + n;
            int e = gn >> 8, o = gn & 255;
            Bs[k][n] = loadf(exp_W, ((size_t)((l * E + e) * D + o)) * D + k0 + k, bf);
        }
        __syncthreads();
        for (int k = 0; k < BK; k++) {
            float a[4], bb[4];
            #pragma unroll
            for (int i = 0; i < 4; i++) a[i] = As[k][tm + i];
            #pragma unroll
            for (int j = 0; j < 4; j++) bb[j] = Bs[k][tn + j];
            #pragma unroll
            for (int i = 0; i < 4; i++)
                #pragma unroll
                for (int j = 0; j < 4; j++)
                    acc[i][j] += a[i] * bb[j];
        }
        __syncthreads();
    }
    #pragma unroll
    for (int i = 0; i < 4; i++)
        #pragma unroll
        for (int j = 0; j < 4; j++)
            Y[(size_t)(bm + tm + i) * NE + bn + tn + j] = acc[i][j];
}

// ---------------- combine 3 selected experts + bias ----------------
__global__ void k_combine(const float* __restrict__ Y, const int* __restrict__ excl,
                          const void* __restrict__ exp_b, const int* __restrict__ bfp,
                          int l, float* __restrict__ xo) {
    int s = blockIdx.x, t = threadIdx.x;
    int bf = *bfp;
    int ex = excl[s];
    float a = 0.f;
    for (int e = 0; e < E; e++) {
        if (e == ex) continue;
        a += Y[(size_t)s * NE + e * D + t] + loadf(exp_b, (size_t)(l * E + e) * D + t, bf);
    }
    xo[s * D + t] = a;
}

// ---------------- final LayerNorm -> bf16 (wave per token) ----------------
__global__ void k_ln(const float* __restrict__ x, const void* __restrict__ g,
                     const void* __restrict__ b, const int* __restrict__ bfp,
                     bf16* __restrict__ xnb) {
    int t = threadIdx.x, w = t >> 6, ln = t & 63;
    int s = blockIdx.x * 4 + w;
    int bf = *bfp;
    float vv[4];
    float sum = 0.f, sq = 0.f;
    #pragma unroll
    for (int j = 0; j < 4; j++) {
        float v = x[(size_t)s * D + ln + j * 64];
        vv[j] = v; sum += v; sq += v * v;
    }
    #pragma unroll
    for (int m2 = 1; m2 < 64; m2 <<= 1) {
        sum += __shfl_xor(sum, m2, 64);
        sq  += __shfl_xor(sq, m2, 64);
    }
    float m = sum / (float)D;
    float var = sq / (float)D - m * m;   // biased
    float r = rsqrtf(var + 1e-5f);
    #pragma unroll
    for (int j = 0; j < 4; j++) {
        int f = ln + j * 64;
        xnb[(size_t)s * D + f] = __float2bfloat16((vv[j] - m) * r * loadf(g, f, bf)
                                                  + loadf(b, f, bf));
    }
}

// ---------------- vocab head: MFMA bf16, 128x128, GLDS staging + CTS epilogue ----
__global__ __launch_bounds__(256) void k_head_mfma(const bf16* __restrict__ xnb,
                                                   const void* __restrict__ head_W_raw,
                                                   const bf16* __restrict__ Wb,
                                                   const void* __restrict__ bias,
                                                   const int* __restrict__ bfp,
                                                   void* __restrict__ out) {
    // union: staging (16 KB) / C-tile 128*CTS shorts (34.8 KB)
    __shared__ __align__(16) char smem[128 * CTS * 2];
    short* At = (short*)smem;            // [128][32] swizzled
    short* Bt = (short*)(smem + 8192);   // [128][32] swizzled
    short* Ct = (short*)smem;            // [128][CTS] bf16 bits
    int bf = *bfp;
    const bf16* Wsrc = bf ? (const bf16*)head_W_raw : Wb;
    int bs = blockIdx.x * 128;   // token tile (x fastest -> W-tile L2 reuse)
    int bv = blockIdx.y * 128;   // vocab tile
    int t = threadIdx.x;
    int wave = t >> 6, lane = t & 63;
    int wm = (wave >> 1) * 64, wn = (wave & 1) * 64;
    int quad = lane >> 4, l16 = lane & 15;

    f32x4 acc[4][4] = {};
    for (int k0 = 0; k0 < D; k0 += 32) {
        stage_tile(xnb + (size_t)bs * D, D, At, t, k0);
        stage_tile(Wsrc + (size_t)bv * D, D, Bt, t, k0);
        __syncthreads();
        bf16x8 af[4], bfg[4];
        #pragma unroll
        for (int i = 0; i < 4; i++) af[i]  = frag_ld(At, wm + i * 16 + l16, quad);
        #pragma unroll
        for (int j = 0; j < 4; j++) bfg[j] = frag_ld(Bt, wn + j * 16 + l16, quad);
        #pragma unroll
        for (int i = 0; i < 4; i++)
            #pragma unroll
            for (int j = 0; j < 4; j++)
                acc[i][j] = __builtin_amdgcn_mfma_f32_16x16x32_bf16(af[i], bfg[j], acc[i][j], 0, 0, 0);
        __syncthreads();
    }
    if (bf) {
        // bias add + pack into LDS C-tile, then 16B/lane coalesced stores
        #pragma unroll
        for (int j = 0; j < 4; j++) {
            int colL = wn + j * 16 + l16;
            float bb = __bfloat162float(((const bf16*)bias)[bv + colL]);
            #pragma unroll
            for (int i = 0; i < 4; i++) {
                int rowL = wm + i * 16 + quad * 4;
                #pragma unroll
                for (int rg = 0; rg < 4; rg++) {
                    bf16 hv = __float2bfloat16(acc[i][j][rg] + bb);
                    Ct[(rowL + rg) * CTS + colL] = *(short*)&hv;
                }
            }
        }
        __syncthreads();
        bf16* ob = (bf16*)out;
        #pragma unroll
        for (int k = 0; k < 8; k++) {
            int cc = k * 256 + t;
            int row = cc >> 4, c16 = cc & 15;
            bf16x8 v = *(const bf16x8*)&Ct[row * CTS + c16 * 8];
            *(bf16x8*)(ob + (size_t)(bs + row) * V + bv + c16 * 8) = v;
        }
    } else {
        float* of = (float*)out;
        #pragma unroll
        for (int j = 0; j < 4; j++) {
            int col = bv + wn + j * 16 + l16;
            float bb = loadf(bias, col, bf);
            #pragma unroll
            for (int i = 0; i < 4; i++) {
                int row0 = bs + wm + i * 16 + quad * 4;
                #pragma unroll
                for (int rg = 0; rg < 4; rg++)
                    of[(size_t)(row0 + rg) * V + col] = acc[i][j][rg] + bb;
            }
        }
    }
}

extern "C" void kernel_launch(void* const* d_in, const int* in_sizes, int n_in,
                              void* d_out, int out_size, void* d_ws, size_t ws_size,
                              hipStream_t stream) {
    const int*  tokens   = (const int*)d_in[0];
    const void* emb      = d_in[1];
    const void* buffers  = d_in[2];
    const void* decays   = d_in[3];
    const void* gate_w   = d_in[4];
    const void* gating_W = d_in[5];
    const void* gating_b = d_in[6];
    const void* exp_W    = d_in[7];
    const void* exp_b    = d_in[8];
    const void* ln_g     = d_in[9];
    const void* ln_b     = d_in[10];
    const void* head_W   = d_in[11];
    const void* head_b   = d_in[12];

    char* p = (char*)d_ws;
    bf16* Wb    = (bf16*)p;             p += (size_t)V * D * 2;       // fp32 fallback
    bf16* xnb   = (bf16*)p;             p += (size_t)S * D * 2;
    float* xA   = (float*)p;            p += (size_t)S * D * 4;
    float* xB   = (float*)p;            p += (size_t)S * D * 4;
    float* xg   = (float*)p;            p += (size_t)S * D * 4;
    float* Y    = (float*)p;            p += (size_t)S * NE * 4;      // 16.8 MB
    float* psum = (float*)p;            p += (size_t)NCH * D * 4;
    float* psq  = (float*)p;            p += (size_t)NCH * D * 4;
    float* scores = (float*)p;          p += (size_t)S * 4;
    float* mu   = (float*)p;            p += D * 4;
    float* rstd = (float*)p;            p += D * 4;
    float* absnb = (float*)p;           p += D * 4;
    float* thr  = (float*)p;            p += 16;
    int* flag   = (int*)p;              p += 16;
    int* excl   = (int*)p;              p += (size_t)S * 4;

    k_detect<<<1, 1, 0, stream>>>(emb, flag);
    k_wcast<<<(V * D) / 1024, 256, 0, stream>>>(head_W, flag, Wb);
    k_embed<<<S, D, 0, stream>>>(tokens, emb, flag, xA);

    float* xc = xA;
    float* xo = xB;
    for (int l = 0; l < L; l++) {
        k_stats_part<<<NCH, 256, 0, stream>>>(xc, psum, psq);
        k_stats_fin<<<1, 256, 0, stream>>>(psum, psq, buffers, decays, flag, l, mu, rstd, absnb);
        k_norm_score<<<S / 4, 256, 0, stream>>>(xc, mu, rstd, absnb, gate_w, flag, l, scores);
        k_thr<<<1, 256, 0, stream>>>(scores, thr);
        k_route<<<S / 4, 256, 0, stream>>>(xc, scores, thr, gating_W, gating_b, flag, l,
                                           xg, excl);
        dim3 ge(NE / BN, S / BM);
        k_egemm<<<ge, 256, 0, stream>>>(xg, exp_W, flag, l, Y);
        k_combine<<<S, 256, 0, stream>>>(Y, excl, exp_b, flag, l, xo);
        float* tmp = xc; xc = xo; xo = tmp;
    }
    k_ln<<<S / 4, 256, 0, stream>>>(xc, ln_g, ln_b, flag, xnb);
    dim3 gh(S / 128, V / 128);
    k_head_mfma<<<gh, 256, 0, stream>>>(xnb, head_W, Wb, head_b, flag, d_out);
}

// Round 9
// 991.654 us; speedup vs baseline: 8.7384x; 1.1902x over previous
//
#include <hip/hip_runtime.h>
#include <hip/hip_bf16.h>
#include <math.h>

#define V 32000
#define D 256
#define L 4
#define E 4
#define S 4096
#define K_GATE 2201   // int(4096 * sigmoid(0.15)) = int(2201.31)
#define NE 1024       // E*D: concatenated expert output width
#define NCH 64        // stats chunks
#define SCHUNK 64     // tokens per stats chunk
#define CTS 136       // head C-tile LDS row stride (shorts); 272B=17*16 -> rows 16B-aligned

// Numerics rule (R4-R7 bisect): the expert GEMM must stay fp32-exact. AstroNorm
// makes ~1M |x-mu|>|buf| comparisons/layer; bf16 split-MFMA noise (even 3-way,
// ~2^-25) flipped some and produced O(1) row errors. fp32 VALU noise (~1e-7) is
// the proven-safe class.

typedef __hip_bfloat16 bf16;
typedef __attribute__((ext_vector_type(8))) short bf16x8;
typedef __attribute__((ext_vector_type(4))) float f32x4;

__device__ __forceinline__ float loadf(const void* p, size_t i, int bf) {
    if (bf) return __bfloat162float(((const bf16*)p)[i]);
    return ((const float*)p)[i];
}
__device__ __forceinline__ float us2f(unsigned short u) {   // bf16 bits -> fp32 (exact)
    return __uint_as_float((unsigned)u << 16);
}

// async global->LDS, 16B per lane; LDS dest = wave-uniform base + lane*16
#define GLDS16(g, l)                                                            \
    __builtin_amdgcn_global_load_lds(                                           \
        (const __attribute__((address_space(1))) unsigned int*)(g),             \
        (__attribute__((address_space(3))) unsigned int*)(l), 16, 0, 0)

// Stage a 128x32 bf16 tile (8 KB) with XOR chunk swizzle (exonerated R5/R6:
// bit-identical outputs). frag ds_read_b128 lands ~2-way conflict (free).
__device__ __forceinline__ void stage_tile(const bf16* __restrict__ src, int rowStride,
                                           short* lds, int t, int k0) {
    int w = t >> 6, l = t & 63;
    #pragma unroll
    for (int i = 0; i < 2; i++) {
        int chunk = (w * 2 + i) * 64 + l;
        int row = chunk >> 2;
        int c8 = (chunk & 3) ^ ((row >> 1) & 3);
        const bf16* g = src + (size_t)row * rowStride + k0 + c8 * 8;
        GLDS16(g, (char*)lds + (size_t)(w * 2 + i) * 1024);
    }
}

__device__ __forceinline__ bf16x8 frag_ld(const short* lds, int row, int quad) {
    return *(const bf16x8*)&lds[row * 32 + ((quad ^ ((row >> 1) & 3)) << 3)];
}

// ---------------- runtime dtype detection (bf16 vs fp32 inputs) ----------------
__global__ void k_detect(const void* __restrict__ emb, int* __restrict__ flag) {
    const unsigned short* h = (const unsigned short*)emb;
    int cnt = 0;
    for (int i = 0; i < 128; i += 2) {
        int e = (h[i] >> 7) & 0xFF;
        if (e >= 100 && e <= 130) cnt++;
    }
    *flag = (cnt >= 32) ? 1 : 0;
}

// ---------------- head weight -> bf16 (fp32-input fallback only) ----------------
__global__ void k_wcast(const void* __restrict__ W, const int* __restrict__ bfp,
                        bf16* __restrict__ Wb) {
    if (*bfp) return;   // bf16 inputs: head reads W directly
    size_t idx = ((size_t)blockIdx.x * 256 + threadIdx.x) * 4;
    float4 v = *(const float4*)((const float*)W + idx);
    Wb[idx + 0] = __float2bfloat16(v.x);
    Wb[idx + 1] = __float2bfloat16(v.y);
    Wb[idx + 2] = __float2bfloat16(v.z);
    Wb[idx + 3] = __float2bfloat16(v.w);
}

// ---------------- embedding gather ----------------
__global__ void k_embed(const int* __restrict__ tok, const void* __restrict__ emb,
                        const int* __restrict__ bfp, float* __restrict__ x) {
    int s = blockIdx.x, d = threadIdx.x;
    int bf = *bfp;
    int t = tok[s];
    x[s * D + d] = loadf(emb, (size_t)t * D + d, bf);
}

// ---------------- AstroNorm stats, phase 1: coalesced partial sums ----------------
__global__ void k_stats_part(const float* __restrict__ x, float* __restrict__ psum,
                             float* __restrict__ psq) {
    int b = blockIdx.x;        // NCH blocks
    int t = threadIdx.x;       // 256 = one feature per thread
    float s = 0.f, q = 0.f;
    int s0 = b * SCHUNK;
    #pragma unroll 4
    for (int i = 0; i < SCHUNK; i++) {
        float v = x[(size_t)(s0 + i) * D + t];
        s += v; q += v * v;
    }
    psum[b * D + t] = s;
    psq[b * D + t] = q;
}

// ---------------- AstroNorm stats, phase 2: finalize ----------------
__global__ void k_stats_fin(const float* __restrict__ psum, const float* __restrict__ psq,
                            const void* __restrict__ buffers, const void* __restrict__ decays,
                            const int* __restrict__ bfp, int l,
                            float* __restrict__ mu, float* __restrict__ rstd,
                            float* __restrict__ absnb) {
    int t = threadIdx.x;       // 256
    int bf = *bfp;
    float s = 0.f, q = 0.f;
    for (int b = 0; b < NCH; b++) { s += psum[b * D + t]; q += psq[b * D + t]; }
    float m = s / (float)S;
    float var = (q - (float)S * m * m) / (float)(S - 1);   // ddof=1
    float dec = loadf(decays, l, bf);
    float nb = dec * loadf(buffers, l * D + t, bf) + (1.f - dec) * m;
    mu[t] = m;
    rstd[t] = rsqrtf(var + 1e-6f);
    absnb[t] = fabsf(nb);
}

// ---------------- AstroNorm apply + context-gate score (wave per token) ----------
__global__ void k_norm_score(float* __restrict__ x, const float* __restrict__ mu,
                             const float* __restrict__ rstd, const float* __restrict__ absnb,
                             const void* __restrict__ gate_w, const int* __restrict__ bfp,
                             int l, float* __restrict__ scores) {
    int t = threadIdx.x, w = t >> 6, ln = t & 63;
    int s = blockIdx.x * 4 + w;
    int bf = *bfp;
    float part = 0.f;
    #pragma unroll
    for (int j = 0; j < 4; j++) {
        int f = ln + j * 64;
        float m = mu[f];
        float v = x[(size_t)s * D + f];
        float xv = (fabsf(v - m) > absnb[f]) ? m : v;
        xv *= rstd[f];
        x[(size_t)s * D + f] = xv;
        part += xv * loadf(gate_w, l * D + f, bf);
    }
    #pragma unroll
    for (int m2 = 1; m2 < 64; m2 <<= 1) part += __shfl_xor(part, m2, 64);
    if (ln == 0) scores[s] = part;
}

// ------- k-th largest via exact MSB radix select (1024 thr, wave-0 scan) ---------
__global__ void k_thr(const float* __restrict__ scores, float* __restrict__ thr) {
    __shared__ unsigned keys[S];
    __shared__ unsigned hist[256];
    __shared__ unsigned sh_pref, sh_rank, sh_bucket;
    int t = threadIdx.x;                     // 1024 threads
    #pragma unroll
    for (int i = 0; i < 4; i++) {
        int idx = i * 1024 + t;
        unsigned u = __float_as_uint(scores[idx]);
        keys[idx] = (u & 0x80000000u) ? ~u : (u | 0x80000000u);   // ascending-monotone
    }
    if (t == 0) { sh_pref = 0u; sh_rank = S - K_GATE; }            // 0-based ascending rank
    __syncthreads();
    for (int shift = 24; shift >= 0; shift -= 8) {
        if (t < 256) hist[t] = 0u;
        __syncthreads();
        unsigned pref = sh_pref, r = sh_rank;
        unsigned pmask = (shift == 24) ? 0u : (0xFFFFFFFFu << (shift + 8));
        #pragma unroll
        for (int i = 0; i < 4; i++) {
            unsigned k = keys[i * 1024 + t];
            if ((k & pmask) == pref) atomicAdd(&hist[(k >> shift) & 0xFF], 1u);
        }
        __syncthreads();
        if (t < 64) {   // wave 0: ordered prefix over 256 buckets, 4/lane
            unsigned h[4];
            unsigned loc = 0u;
            #pragma unroll
            for (int j = 0; j < 4; j++) { h[j] = hist[t * 4 + j]; loc += h[j]; }
            unsigned pre = loc;
            #pragma unroll
            for (int off = 1; off < 64; off <<= 1) {
                unsigned u2 = __shfl_up(pre, off, 64);
                if (t >= off) pre += u2;
            }
            unsigned base = pre - loc;          // exclusive prefix of this lane's chunk
            if (r >= base && r < pre) {         // exactly one lane matches
                unsigned rr = r - base;
                int bsel = -1;
                #pragma unroll
                for (int j = 0; j < 4; j++) {
                    if (bsel < 0) {
                        if (rr < h[j]) bsel = j;
                        else rr -= h[j];
                    }
                }
                sh_bucket = (unsigned)(t * 4 + bsel);
                sh_rank = rr;
            }
        }
        __syncthreads();
        if (t == 0) sh_pref = pref | (sh_bucket << shift);
        __syncthreads();
    }
    if (t == 0) {
        unsigned k = sh_pref;
        unsigned u = (k & 0x80000000u) ? (k ^ 0x80000000u) : ~k;
        thr[0] = __uint_as_float(u);
    }
}

// ---------------- all-expert GEMM, fp32 VALU, 128x128 tile, 8x8/thread -----------
// Y[s][gn] = (x[s,:]*keep[s]) . exp_W[l,gn,:]. Gate applied during A staging.
// Same k-ascending fp32 accumulation order as the R3-proven kernel.
#define EBM 128
#define EBN 128
#define EBK 32
__global__ __launch_bounds__(256) void k_egemm(const float* __restrict__ x,
                                               const float* __restrict__ scores,
                                               const float* __restrict__ thr,
                                               const void* __restrict__ exp_W,
                                               const int* __restrict__ bfp, int l,
                                               float* __restrict__ Y) {
    __shared__ float As[EBK][EBM + 4];   // row = 132 floats = 528 B (33*16: aligned)
    __shared__ float Bs[EBK][EBN + 4];
    __shared__ float kp[EBM];
    int bf = *bfp;
    int bn = blockIdx.x * EBN;   // expert-output col tile [0,NE)
    int bm = blockIdx.y * EBM;   // token tile
    int t = threadIdx.x;
    int tm = (t >> 4) * 8;
    int tn = (t & 15) * 8;
    if (t < EBM) kp[t] = (scores[bm + t] > thr[0]) ? 1.f : 0.f;
    __syncthreads();
    const unsigned short* Wb16 = (const unsigned short*)exp_W;
    const float* Wf32 = (const float*)exp_W;
    size_t wbase = (size_t)l * NE * D;
    float acc[8][8] = {};
    for (int k0 = 0; k0 < D; k0 += EBK) {
        #pragma unroll
        for (int i = 0; i < 4; i++) {               // A: 128x32 floats, gated
            int chunk = i * 256 + t;
            int m = chunk >> 3, c4 = chunk & 7;
            float4 v = *(const float4*)&x[(size_t)(bm + m) * D + k0 + c4 * 4];
            float kk = kp[m];
            As[c4 * 4 + 0][m] = v.x * kk;
            As[c4 * 4 + 1][m] = v.y * kk;
            As[c4 * 4 + 2][m] = v.z * kk;
            As[c4 * 4 + 3][m] = v.w * kk;
        }
        if (bf) {
            #pragma unroll
            for (int i = 0; i < 2; i++) {           // B: 128x32 bf16 -> fp32 exact
                int chunk = i * 256 + t;
                int n = chunk >> 2, c8 = chunk & 3;
                const unsigned short* src = Wb16 + wbase + (size_t)(bn + n) * D + k0 + c8 * 8;
                ushort4 v0 = *(const ushort4*)src;
                ushort4 v1 = *(const ushort4*)(src + 4);
                Bs[c8 * 8 + 0][n] = us2f(v0.x);
                Bs[c8 * 8 + 1][n] = us2f(v0.y);
                Bs[c8 * 8 + 2][n] = us2f(v0.z);
                Bs[c8 * 8 + 3][n] = us2f(v0.w);
                Bs[c8 * 8 + 4][n] = us2f(v1.x);
                Bs[c8 * 8 + 5][n] = us2f(v1.y);
                Bs[c8 * 8 + 6][n] = us2f(v1.z);
                Bs[c8 * 8 + 7][n] = us2f(v1.w);
            }
        } else {
            #pragma unroll
            for (int i = 0; i < 4; i++) {
                int chunk = i * 256 + t;
                int n = chunk >> 3, c4 = chunk & 7;
                float4 v = *(const float4*)&Wf32[wbase + (size_t)(bn + n) * D + k0 + c4 * 4];
                Bs[c4 * 4 + 0][n] = v.x;
                Bs[c4 * 4 + 1][n] = v.y;
                Bs[c4 * 4 + 2][n] = v.z;
                Bs[c4 * 4 + 3][n] = v.w;
            }
        }
        __syncthreads();
        #pragma unroll 4
        for (int k = 0; k < EBK; k++) {
            float a[8], b[8];
            *(float4*)&a[0] = *(const float4*)&As[k][tm];
            *(float4*)&a[4] = *(const float4*)&As[k][tm + 4];
            *(float4*)&b[0] = *(const float4*)&Bs[k][tn];
            *(float4*)&b[4] = *(const float4*)&Bs[k][tn + 4];
            #pragma unroll
            for (int i = 0; i < 8; i++)
                #pragma unroll
                for (int j = 0; j < 8; j++)
                    acc[i][j] += a[i] * b[j];
        }
        __syncthreads();
    }
    #pragma unroll
    for (int i = 0; i < 8; i++) {
        float4 o0 = { acc[i][0], acc[i][1], acc[i][2], acc[i][3] };
        float4 o1 = { acc[i][4], acc[i][5], acc[i][6], acc[i][7] };
        float* dst = &Y[(size_t)(bm + tm + i) * NE + bn + tn];
        *(float4*)dst = o0;
        *(float4*)(dst + 4) = o1;
    }
}

// -------- fused router + combine (wave per token): gs -> excl -> 3-expert sum ----
__global__ void k_comb(const float* __restrict__ x, const float* __restrict__ scores,
                       const float* __restrict__ thr,
                       const void* __restrict__ gating_W, const void* __restrict__ gating_b,
                       const float* __restrict__ Y, const void* __restrict__ exp_b,
                       const int* __restrict__ bfp, int l, float* __restrict__ xo) {
    int t = threadIdx.x, w = t >> 6, ln = t & 63;
    int s = blockIdx.x * 4 + w;
    int bf = *bfp;
    float keep = (scores[s] > thr[0]) ? 1.f : 0.f;
    float xv[4];
    #pragma unroll
    for (int j = 0; j < 4; j++)
        xv[j] = x[(size_t)s * D + ln + j * 64] * keep;
    float gs[E];
    #pragma unroll
    for (int e = 0; e < E; e++) {
        float p = 0.f;
        #pragma unroll
        for (int j = 0; j < 4; j++)
            p += xv[j] * loadf(gating_W, (size_t)(l * E + e) * D + ln + j * 64, bf);
        #pragma unroll
        for (int m2 = 1; m2 < 64; m2 <<= 1) p += __shfl_xor(p, m2, 64);
        gs[e] = p + loadf(gating_b, l * E + e, bf);
    }
    int mi = 0;
    if (ln == 0) {
        // excluded = argmin; ties -> largest index (top_k keeps lower indices)
        float mv = gs[0];
        #pragma unroll
        for (int e = 1; e < E; e++) if (gs[e] <= mv) { mv = gs[e]; mi = e; }
    }
    int excl = __shfl(mi, 0, 64);
    #pragma unroll
    for (int j = 0; j < 4; j++) {
        int f = ln + j * 64;
        float a = 0.f;
        for (int e = 0; e < E; e++) {
            if (e == excl) continue;
            a += Y[(size_t)s * NE + e * D + f] + loadf(exp_b, (size_t)(l * E + e) * D + f, bf);
        }
        xo[(size_t)s * D + f] = a;
    }
}

// ---------------- final LayerNorm -> bf16 (wave per token) ----------------
__global__ void k_ln(const float* __restrict__ x, const void* __restrict__ g,
                     const void* __restrict__ b, const int* __restrict__ bfp,
                     bf16* __restrict__ xnb) {
    int t = threadIdx.x, w = t >> 6, ln = t & 63;
    int s = blockIdx.x * 4 + w;
    int bf = *bfp;
    float vv[4];
    float sum = 0.f, sq = 0.f;
    #pragma unroll
    for (int j = 0; j < 4; j++) {
        float v = x[(size_t)s * D + ln + j * 64];
        vv[j] = v; sum += v; sq += v * v;
    }
    #pragma unroll
    for (int m2 = 1; m2 < 64; m2 <<= 1) {
        sum += __shfl_xor(sum, m2, 64);
        sq  += __shfl_xor(sq, m2, 64);
    }
    float m = sum / (float)D;
    float var = sq / (float)D - m * m;   // biased
    float r = rsqrtf(var + 1e-5f);
    #pragma unroll
    for (int j = 0; j < 4; j++) {
        int f = ln + j * 64;
        xnb[(size_t)s * D + f] = __float2bfloat16((vv[j] - m) * r * loadf(g, f, bf)
                                                  + loadf(b, f, bf));
    }
}

// ---------------- vocab head: MFMA bf16, 128x128, GLDS staging + CTS epilogue ----
__global__ __launch_bounds__(256) void k_head_mfma(const bf16* __restrict__ xnb,
                                                   const void* __restrict__ head_W_raw,
                                                   const bf16* __restrict__ Wb,
                                                   const void* __restrict__ bias,
                                                   const int* __restrict__ bfp,
                                                   void* __restrict__ out) {
    // union: staging (16 KB) / C-tile 128*CTS shorts (34.8 KB)
    __shared__ __align__(16) char smem[128 * CTS * 2];
    short* At = (short*)smem;            // [128][32] swizzled
    short* Bt = (short*)(smem + 8192);   // [128][32] swizzled
    short* Ct = (short*)smem;            // [128][CTS] bf16 bits
    int bf = *bfp;
    const bf16* Wsrc = bf ? (const bf16*)head_W_raw : Wb;
    int bs = blockIdx.x * 128;   // token tile (x fastest -> W-tile L2 reuse)
    int bv = blockIdx.y * 128;   // vocab tile
    int t = threadIdx.x;
    int wave = t >> 6, lane = t & 63;
    int wm = (wave >> 1) * 64, wn = (wave & 1) * 64;
    int quad = lane >> 4, l16 = lane & 15;

    f32x4 acc[4][4] = {};
    for (int k0 = 0; k0 < D; k0 += 32) {
        stage_tile(xnb + (size_t)bs * D, D, At, t, k0);
        stage_tile(Wsrc + (size_t)bv * D, D, Bt, t, k0);
        __syncthreads();
        bf16x8 af[4], bfg[4];
        #pragma unroll
        for (int i = 0; i < 4; i++) af[i]  = frag_ld(At, wm + i * 16 + l16, quad);
        #pragma unroll
        for (int j = 0; j < 4; j++) bfg[j] = frag_ld(Bt, wn + j * 16 + l16, quad);
        #pragma unroll
        for (int i = 0; i < 4; i++)
            #pragma unroll
            for (int j = 0; j < 4; j++)
                acc[i][j] = __builtin_amdgcn_mfma_f32_16x16x32_bf16(af[i], bfg[j], acc[i][j], 0, 0, 0);
        __syncthreads();
    }
    if (bf) {
        // bias add + pack into LDS C-tile, then 16B/lane coalesced stores
        #pragma unroll
        for (int j = 0; j < 4; j++) {
            int colL = wn + j * 16 + l16;
            float bb = __bfloat162float(((const bf16*)bias)[bv + colL]);
            #pragma unroll
            for (int i = 0; i < 4; i++) {
                int rowL = wm + i * 16 + quad * 4;
                #pragma unroll
                for (int rg = 0; rg < 4; rg++) {
                    bf16 hv = __float2bfloat16(acc[i][j][rg] + bb);
                    Ct[(rowL + rg) * CTS + colL] = *(short*)&hv;
                }
            }
        }
        __syncthreads();
        bf16* ob = (bf16*)out;
        #pragma unroll
        for (int k = 0; k < 8; k++) {
            int cc = k * 256 + t;
            int row = cc >> 4, c16 = cc & 15;
            bf16x8 v = *(const bf16x8*)&Ct[row * CTS + c16 * 8];
            *(bf16x8*)(ob + (size_t)(bs + row) * V + bv + c16 * 8) = v;
        }
    } else {
        float* of = (float*)out;
        #pragma unroll
        for (int j = 0; j < 4; j++) {
            int col = bv + wn + j * 16 + l16;
            float bb = loadf(bias, col, bf);
            #pragma unroll
            for (int i = 0; i < 4; i++) {
                int row0 = bs + wm + i * 16 + quad * 4;
                #pragma unroll
                for (int rg = 0; rg < 4; rg++)
                    of[(size_t)(row0 + rg) * V + col] = acc[i][j][rg] + bb;
            }
        }
    }
}

extern "C" void kernel_launch(void* const* d_in, const int* in_sizes, int n_in,
                              void* d_out, int out_size, void* d_ws, size_t ws_size,
                              hipStream_t stream) {
    const int*  tokens   = (const int*)d_in[0];
    const void* emb      = d_in[1];
    const void* buffers  = d_in[2];
    const void* decays   = d_in[3];
    const void* gate_w   = d_in[4];
    const void* gating_W = d_in[5];
    const void* gating_b = d_in[6];
    const void* exp_W    = d_in[7];
    const void* exp_b    = d_in[8];
    const void* ln_g     = d_in[9];
    const void* ln_b     = d_in[10];
    const void* head_W   = d_in[11];
    const void* head_b   = d_in[12];

    char* p = (char*)d_ws;
    bf16* Wb    = (bf16*)p;             p += (size_t)V * D * 2;       // fp32 fallback
    bf16* xnb   = (bf16*)p;             p += (size_t)S * D * 2;
    float* xA   = (float*)p;            p += (size_t)S * D * 4;
    float* xB   = (float*)p;            p += (size_t)S * D * 4;
    float* Y    = (float*)p;            p += (size_t)S * NE * 4;      // 16.8 MB
    float* psum = (float*)p;            p += (size_t)NCH * D * 4;
    float* psq  = (float*)p;            p += (size_t)NCH * D * 4;
    float* scores = (float*)p;          p += (size_t)S * 4;
    float* mu   = (float*)p;            p += D * 4;
    float* rstd = (float*)p;            p += D * 4;
    float* absnb = (float*)p;           p += D * 4;
    float* thr  = (float*)p;            p += 16;
    int* flag   = (int*)p;              p += 16;

    k_detect<<<1, 1, 0, stream>>>(emb, flag);
    k_wcast<<<(V * D) / 1024, 256, 0, stream>>>(head_W, flag, Wb);
    k_embed<<<S, D, 0, stream>>>(tokens, emb, flag, xA);

    float* xc = xA;
    float* xo = xB;
    for (int l = 0; l < L; l++) {
        k_stats_part<<<NCH, 256, 0, stream>>>(xc, psum, psq);
        k_stats_fin<<<1, 256, 0, stream>>>(psum, psq, buffers, decays, flag, l, mu, rstd, absnb);
        k_norm_score<<<S / 4, 256, 0, stream>>>(xc, mu, rstd, absnb, gate_w, flag, l, scores);
        k_thr<<<1, 1024, 0, stream>>>(scores, thr);
        dim3 ge(NE / EBN, S / EBM);
        k_egemm<<<ge, 256, 0, stream>>>(xc, scores, thr, exp_W, flag, l, Y);
        k_comb<<<S / 4, 256, 0, stream>>>(xc, scores, thr, gating_W, gating_b, Y,
                                          exp_b, flag, l, xo);
        float* tmp = xc; xc = xo; xo = tmp;
    }
    k_ln<<<S / 4, 256, 0, stream>>>(xc, ln_g, ln_b, flag, xnb);
    dim3 gh(S / 128, V / 128);
    k_head_mfma<<<gh, 256, 0, stream>>>(xnb, head_W, Wb, head_b, flag, d_out);
}